// Round 1
// baseline (171.794 us; speedup 1.0000x reference)
//
#include <hip/hip_runtime.h>

// AttentionLayer: B=2,T=12,N=1024,D=128,H=8,HD=16
// Pipeline: [qkv_proj: x@W.T+b -> bf16 head-major ws] -> [attn: streaming softmax,
// 16x16x32 bf16 MFMA, K zero-padded to 32, V transposed in LDS] -> [o_proj -> f32 out]
// scale 1/sqrt(16)*log2(e) folded into stored q so softmax uses exp2 directly.

#define DEV __device__ __forceinline__

typedef __attribute__((ext_vector_type(4))) float f32x4;
typedef __attribute__((ext_vector_type(8))) short s16x8;   // 8 bf16 (4 VGPRs)

DEV unsigned short f2bf(float f) {          // fp32 -> bf16, round-nearest-even
    unsigned u = __builtin_bit_cast(unsigned, f);
    u = (u + 0x7fffu + ((u >> 16) & 1u)) >> 16;
    return (unsigned short)u;
}

// ---------------------------------------------------------------- qkv proj ---
// grid (384, 3): x = 64-row tile of M=24576, y = which of q/k/v.
// out layout: [bt][h][n][hd] bf16;  q pre-scaled by 0.25*log2e.
__global__ __launch_bounds__(256)
void qkv_proj_kernel(const float* __restrict__ xq, const float* __restrict__ xk,
                     const float* __restrict__ xv,
                     const float* __restrict__ Wq, const float* __restrict__ Wk,
                     const float* __restrict__ Wv,
                     const float* __restrict__ bq, const float* __restrict__ bk,
                     const float* __restrict__ bv,
                     unsigned short* __restrict__ oq, unsigned short* __restrict__ ok,
                     unsigned short* __restrict__ ov)
{
    const int z = blockIdx.y;
    const float* X    = (z == 0) ? xq : (z == 1) ? xk : xv;
    const float* W    = (z == 0) ? Wq : (z == 1) ? Wk : Wv;
    const float* bias = (z == 0) ? bq : (z == 1) ? bk : bv;
    unsigned short* out = (z == 0) ? oq : (z == 1) ? ok : ov;
    const float scale = (z == 0) ? 0.25f * 1.44269504088896f : 1.0f;

    __shared__ unsigned short Xs[64 * 136];    // 64x128 bf16, stride 136 (pad 8)
    __shared__ unsigned short Ws[128 * 136];   // 128x128 bf16

    const int t  = threadIdx.x;
    const int m0 = blockIdx.x * 64;

    {   // stage X tile (fp32 -> bf16)
        const float4* Xg = (const float4*)(X + (size_t)m0 * 128);
        #pragma unroll
        for (int p = 0; p < 8; p++) {
            int g = p * 256 + t;               // 0..2047 float4s
            float4 vv = Xg[g];
            int row = g >> 5, c4 = g & 31;
            ushort4 d;
            d.x = f2bf(vv.x); d.y = f2bf(vv.y); d.z = f2bf(vv.z); d.w = f2bf(vv.w);
            *(ushort4*)&Xs[row * 136 + c4 * 4] = d;
        }
        // stage W (128x128 fp32 -> bf16)
        const float4* Wg = (const float4*)W;
        #pragma unroll
        for (int p = 0; p < 16; p++) {
            int g = p * 256 + t;               // 0..4095
            float4 vv = Wg[g];
            int row = g >> 5, c4 = g & 31;
            ushort4 d;
            d.x = f2bf(vv.x); d.y = f2bf(vv.y); d.z = f2bf(vv.z); d.w = f2bf(vv.w);
            *(ushort4*)&Ws[row * 136 + c4 * 4] = d;
        }
    }
    __syncthreads();

    const int wave = t >> 6, lane = t & 63, quad = lane >> 4, n16 = lane & 15;
    f32x4 acc[8];
    const f32x4 zero4 = {0.f, 0.f, 0.f, 0.f};
    #pragma unroll
    for (int i = 0; i < 8; i++) acc[i] = zero4;

    #pragma unroll
    for (int ks = 0; ks < 4; ks++) {
        s16x8 a = *(const s16x8*)&Xs[(wave * 16 + n16) * 136 + ks * 32 + quad * 8];
        #pragma unroll
        for (int nt = 0; nt < 8; nt++) {
            s16x8 b = *(const s16x8*)&Ws[(nt * 16 + n16) * 136 + ks * 32 + quad * 8];
            acc[nt] = __builtin_amdgcn_mfma_f32_16x16x32_bf16(a, b, acc[nt], 0, 0, 0);
        }
    }

    // epilogue: +bias, *scale, bf16, store head-major. col tile nt == head.
    const int bt    = m0 >> 10;
    const int nbase = (m0 & 1023) + wave * 16 + quad * 4;
    #pragma unroll
    for (int nt = 0; nt < 8; nt++) {
        float bb = bias[nt * 16 + n16];
        #pragma unroll
        for (int r = 0; r < 4; r++) {
            float v = (acc[nt][r] + bb) * scale;
            out[((size_t)(bt * 8 + nt) * 1024 + (nbase + r)) * 16 + n16] = f2bf(v);
        }
    }
}

// ---------------------------------------------------------------- attention ---
// grid (16, 8, 24): x = 64-row q block, y = head, z = bt.  256 thr = 4 waves,
// 16 q-rows/wave.  Streaming softmax (no max shift; logits ~ +-0.5).
__global__ __launch_bounds__(256)
void attn_kernel(const unsigned short* __restrict__ q,
                 const unsigned short* __restrict__ k,
                 const unsigned short* __restrict__ v,
                 float* __restrict__ O)
{
    __shared__ unsigned short Ks[256 * 40];   // K chunk, hd 0..15 data, 16..31 zeros, stride 40
    __shared__ unsigned short VTs[16 * 264];  // V^T chunk [hd][j], stride 264
    __shared__ unsigned short Ps[4 * 16 * 40];// per-wave P tile 16x32, stride 40

    const int t    = threadIdx.x;
    const int wave = t >> 6, lane = t & 63, quad = lane >> 4, n16 = lane & 15;
    const int bx = blockIdx.x, h = blockIdx.y, bt = blockIdx.z;
    const size_t headoff = (size_t)(bt * 8 + h) * 1024 * 16;

    {   // zero the hd=16..31 half of Ks once (stays zero across chunks)
        ushort4 z4 = {0, 0, 0, 0};
        *(ushort4*)&Ks[t * 40 + 16] = z4;
        *(ushort4*)&Ks[t * 40 + 20] = z4;
        *(ushort4*)&Ks[t * 40 + 24] = z4;
        *(ushort4*)&Ks[t * 40 + 28] = z4;
    }

    // A_q fragment: A[m=n16][kk=quad*8+i]; kk>=16 must be zero (K padded to 32)
    const int qrow = bx * 64 + wave * 16 + n16;
    s16x8 aq = *(const s16x8*)(q + headoff + (size_t)qrow * 16 + (quad & 1) * 8);
    if (quad >= 2) {
        s16x8 zz = {0, 0, 0, 0, 0, 0, 0, 0};
        aq = zz;
    }

    const f32x4 zero4 = {0.f, 0.f, 0.f, 0.f};
    f32x4 oacc = zero4;
    float dp[4] = {0.f, 0.f, 0.f, 0.f};
    unsigned short* Pw = &Ps[wave * 640];
    const int pwbase = (quad * 4) * 40 + n16;      // P write base (+r*40, +16)
    const int apbase = n16 * 40 + quad * 8;        // P read  (A-frag)

    for (int c = 0; c < 4; c++) {                  // 4 chunks of 256 j
        __syncthreads();
        #pragma unroll
        for (int p = 0; p < 2; p++) {              // stage K chunk
            int g = p * 256 + t, row = g >> 1, half = g & 1;
            s16x8 kv = *(const s16x8*)(k + headoff + (size_t)(c * 256 + row) * 16 + half * 8);
            *(s16x8*)&Ks[row * 40 + half * 8] = kv;
        }
        #pragma unroll
        for (int p = 0; p < 2; p++) {              // stage V chunk, transposed
            int g = p * 256 + t, row = g >> 1, half = g & 1;
            s16x8 vv = *(const s16x8*)(v + headoff + (size_t)(c * 256 + row) * 16 + half * 8);
            #pragma unroll
            for (int i = 0; i < 8; i++)
                VTs[(half * 8 + i) * 264 + row] = (unsigned short)vv[i];
        }
        __syncthreads();

        #pragma unroll
        for (int cc = 0; cc < 8; cc++) {           // 8 sub-chunks of 32 j
            const int jb = cc * 32;
            s16x8 bk0 = *(const s16x8*)&Ks[(jb + n16) * 40 + quad * 8];
            s16x8 bk1 = *(const s16x8*)&Ks[(jb + 16 + n16) * 40 + quad * 8];
            f32x4 s0 = __builtin_amdgcn_mfma_f32_16x16x32_bf16(aq, bk0, zero4, 0, 0, 0);
            f32x4 s1 = __builtin_amdgcn_mfma_f32_16x16x32_bf16(aq, bk1, zero4, 0, 0, 0);
            #pragma unroll
            for (int r = 0; r < 4; r++) {
                float p0 = __builtin_amdgcn_exp2f(s0[r]);   // scale folded into q
                float p1 = __builtin_amdgcn_exp2f(s1[r]);
                dp[r] += p0 + p1;
                Pw[pwbase + r * 40]      = f2bf(p0);        // C-layout -> LDS
                Pw[pwbase + r * 40 + 16] = f2bf(p1);
            }
            // same-wave LDS ops are in-order; aliasing blocks compiler reorder
            s16x8 ap = *(const s16x8*)&Pw[apbase];          // A-layout read-back
            s16x8 bv = *(const s16x8*)&VTs[n16 * 264 + jb + quad * 8];
            oacc = __builtin_amdgcn_mfma_f32_16x16x32_bf16(ap, bv, oacc, 0, 0, 0);
        }
    }

    // reduce denominator over the 16 lanes of this quad (cols), then write
    #pragma unroll
    for (int r = 0; r < 4; r++) {
        float s = dp[r];
        s += __shfl_xor(s, 1);
        s += __shfl_xor(s, 2);
        s += __shfl_xor(s, 4);
        s += __shfl_xor(s, 8);
        dp[r] = s;
    }
    const int orow = bx * 64 + wave * 16 + quad * 4;
    #pragma unroll
    for (int r = 0; r < 4; r++) {
        O[((size_t)bt * 1024 + orow + r) * 128 + h * 16 + n16] = oacc[r] / dp[r];
    }
}

// ---------------------------------------------------------------- out proj ---
__global__ __launch_bounds__(256)
void o_proj_kernel(const float* __restrict__ X, const float* __restrict__ W,
                   const float* __restrict__ bias, float* __restrict__ out)
{
    __shared__ unsigned short Xs[64 * 136];
    __shared__ unsigned short Ws[128 * 136];

    const int t  = threadIdx.x;
    const int m0 = blockIdx.x * 64;

    {
        const float4* Xg = (const float4*)(X + (size_t)m0 * 128);
        #pragma unroll
        for (int p = 0; p < 8; p++) {
            int g = p * 256 + t;
            float4 vv = Xg[g];
            int row = g >> 5, c4 = g & 31;
            ushort4 d;
            d.x = f2bf(vv.x); d.y = f2bf(vv.y); d.z = f2bf(vv.z); d.w = f2bf(vv.w);
            *(ushort4*)&Xs[row * 136 + c4 * 4] = d;
        }
        const float4* Wg = (const float4*)W;
        #pragma unroll
        for (int p = 0; p < 16; p++) {
            int g = p * 256 + t;
            float4 vv = Wg[g];
            int row = g >> 5, c4 = g & 31;
            ushort4 d;
            d.x = f2bf(vv.x); d.y = f2bf(vv.y); d.z = f2bf(vv.z); d.w = f2bf(vv.w);
            *(ushort4*)&Ws[row * 136 + c4 * 4] = d;
        }
    }
    __syncthreads();

    const int wave = t >> 6, lane = t & 63, quad = lane >> 4, n16 = lane & 15;
    f32x4 acc[8];
    const f32x4 zero4 = {0.f, 0.f, 0.f, 0.f};
    #pragma unroll
    for (int i = 0; i < 8; i++) acc[i] = zero4;

    #pragma unroll
    for (int ks = 0; ks < 4; ks++) {
        s16x8 a = *(const s16x8*)&Xs[(wave * 16 + n16) * 136 + ks * 32 + quad * 8];
        #pragma unroll
        for (int nt = 0; nt < 8; nt++) {
            s16x8 b = *(const s16x8*)&Ws[(nt * 16 + n16) * 136 + ks * 32 + quad * 8];
            acc[nt] = __builtin_amdgcn_mfma_f32_16x16x32_bf16(a, b, acc[nt], 0, 0, 0);
        }
    }

    const int mrow = m0 + wave * 16 + quad * 4;
    #pragma unroll
    for (int nt = 0; nt < 8; nt++) {
        float bb = bias[nt * 16 + n16];
        #pragma unroll
        for (int r = 0; r < 4; r++)
            out[(size_t)(mrow + r) * 128 + nt * 16 + n16] = acc[nt][r] + bb;
    }
}

// ------------------------------------------------------------------ launch ---
extern "C" void kernel_launch(void* const* d_in, const int* in_sizes, int n_in,
                              void* d_out, int out_size, void* d_ws, size_t ws_size,
                              hipStream_t stream)
{
    const float* query = (const float*)d_in[0];
    const float* key_  = (const float*)d_in[1];
    const float* value = (const float*)d_in[2];
    const float* Wq = (const float*)d_in[3];
    const float* bq = (const float*)d_in[4];
    const float* Wk = (const float*)d_in[5];
    const float* bk = (const float*)d_in[6];
    const float* Wv = (const float*)d_in[7];
    const float* bv = (const float*)d_in[8];
    const float* Wo = (const float*)d_in[9];
    const float* bo = (const float*)d_in[10];
    float* out = (float*)d_out;

    // workspace layout (30 MB): q,k,v bf16 head-major (6.29 MB each) + O fp32 (12.6 MB)
    char* ws = (char*)d_ws;
    unsigned short* qb = (unsigned short*)(ws);
    unsigned short* kb = (unsigned short*)(ws + 6291456);
    unsigned short* vb = (unsigned short*)(ws + 12582912);
    float*          Ob = (float*)(ws + 18874368);

    qkv_proj_kernel<<<dim3(384, 3, 1), 256, 0, stream>>>(
        query, key_, value, Wq, Wk, Wv, bq, bk, bv, qb, kb, vb);
    attn_kernel<<<dim3(16, 8, 24), 256, 0, stream>>>(qb, kb, vb, Ob);
    o_proj_kernel<<<dim3(384, 1, 1), 256, 0, stream>>>(Ob, Wo, bo, out);
}

// Round 3
// 162.206 us; speedup vs baseline: 1.0591x; 1.0591x over previous
//
#include <hip/hip_runtime.h>

// AttentionLayer: B=2,T=12,N=1024,D=128,H=8,HD=16
// qkv_proj: x@W.T+b -> bf16; q,k head-major [bt][h][n][hd], v TRANSPOSED [bt][h][hd][n].
// attn: S^T = K*Q via mfma 16x16x16 (K=HD=16, no padding). S^T C-layout == PV A-frag
// layout for 16x16x16, so P never touches LDS (in-register exp2 + bf16 pack).
// o_proj -> f32 out.  softmax scale 1/4*log2(e) folded into stored q (exp2 path).

#define DEV __device__ __forceinline__

typedef __attribute__((ext_vector_type(4))) float f32x4;
typedef __attribute__((ext_vector_type(8))) short s16x8;
typedef __attribute__((ext_vector_type(4))) short s16x4;
typedef __attribute__((ext_vector_type(2))) unsigned int u32x2;

DEV unsigned short f2bf(float f) {          // fp32 -> bf16, round-nearest-even
    unsigned u = __builtin_bit_cast(unsigned, f);
    u = (u + 0x7fffu + ((u >> 16) & 1u)) >> 16;
    return (unsigned short)u;
}

DEV unsigned pack_bf16(float a, float b) {  // {lo=bf16(a), hi=bf16(b)}
    unsigned ua = __builtin_bit_cast(unsigned, a);
    unsigned ub = __builtin_bit_cast(unsigned, b);
    ua = ua + 0x7fffu + ((ua >> 16) & 1u);
    ub = ub + 0x7fffu + ((ub >> 16) & 1u);
    return __builtin_amdgcn_perm(ub, ua, 0x07060302);  // {ub.hi16, ua.hi16}
}

DEV f32x4 mfma16(s16x4 a, s16x4 b, f32x4 c) {
#if __has_builtin(__builtin_amdgcn_mfma_f32_16x16x16bf16_1k)
    return __builtin_amdgcn_mfma_f32_16x16x16bf16_1k(a, b, c, 0, 0, 0);
#else
    // emulate with 16x16x32: both operands place data in i<4 of each quad-group
    s16x8 a8 = {a[0], a[1], a[2], a[3], 0, 0, 0, 0};
    s16x8 b8 = {b[0], b[1], b[2], b[3], 0, 0, 0, 0};
    return __builtin_amdgcn_mfma_f32_16x16x32_bf16(a8, b8, c, 0, 0, 0);
#endif
}

// ---------------------------------------------------------------- qkv proj ---
// grid (384, 3): x = 64-row tile of M=24576, y = which of q/k/v.
__global__ __launch_bounds__(256)
void qkv_proj_kernel(const float* __restrict__ xq, const float* __restrict__ xk,
                     const float* __restrict__ xv,
                     const float* __restrict__ Wq, const float* __restrict__ Wk,
                     const float* __restrict__ Wv,
                     const float* __restrict__ bq, const float* __restrict__ bk,
                     const float* __restrict__ bv,
                     unsigned short* __restrict__ oq, unsigned short* __restrict__ ok,
                     unsigned short* __restrict__ ov)
{
    const int z = blockIdx.y;
    const float* X    = (z == 0) ? xq : (z == 1) ? xk : xv;
    const float* W    = (z == 0) ? Wq : (z == 1) ? Wk : Wv;
    const float* bias = (z == 0) ? bq : (z == 1) ? bk : bv;
    unsigned short* out = (z == 0) ? oq : (z == 1) ? ok : ov;
    const float scale = (z == 0) ? 0.25f * 1.44269504088896f : 1.0f;

    __shared__ unsigned short Xs[64 * 136];
    __shared__ unsigned short Ws[128 * 136];

    const int t  = threadIdx.x;
    const int m0 = blockIdx.x * 64;

    {
        const float4* Xg = (const float4*)(X + (size_t)m0 * 128);
        #pragma unroll
        for (int p = 0; p < 8; p++) {
            int g = p * 256 + t;
            float4 vv = Xg[g];
            int row = g >> 5, c4 = g & 31;
            ushort4 d;
            d.x = f2bf(vv.x); d.y = f2bf(vv.y); d.z = f2bf(vv.z); d.w = f2bf(vv.w);
            *(ushort4*)&Xs[row * 136 + c4 * 4] = d;
        }
        const float4* Wg = (const float4*)W;
        #pragma unroll
        for (int p = 0; p < 16; p++) {
            int g = p * 256 + t;
            float4 vv = Wg[g];
            int row = g >> 5, c4 = g & 31;
            ushort4 d;
            d.x = f2bf(vv.x); d.y = f2bf(vv.y); d.z = f2bf(vv.z); d.w = f2bf(vv.w);
            *(ushort4*)&Ws[row * 136 + c4 * 4] = d;
        }
    }
    __syncthreads();

    const int wave = t >> 6, lane = t & 63, quad = lane >> 4, n16 = lane & 15;
    f32x4 acc[8];
    const f32x4 zero4 = {0.f, 0.f, 0.f, 0.f};
    #pragma unroll
    for (int i = 0; i < 8; i++) acc[i] = zero4;

    #pragma unroll
    for (int ks = 0; ks < 4; ks++) {
        s16x8 a = *(const s16x8*)&Xs[(wave * 16 + n16) * 136 + ks * 32 + quad * 8];
        #pragma unroll
        for (int nt = 0; nt < 8; nt++) {
            s16x8 b = *(const s16x8*)&Ws[(nt * 16 + n16) * 136 + ks * 32 + quad * 8];
            acc[nt] = __builtin_amdgcn_mfma_f32_16x16x32_bf16(a, b, acc[nt], 0, 0, 0);
        }
    }

    const int bt    = m0 >> 10;
    const int nbase = (m0 & 1023) + wave * 16 + quad * 4;
    if (z == 2) {
        // V stored transposed: [bt][h][hd][n], h = nt, hd = n16
        #pragma unroll
        for (int nt = 0; nt < 8; nt++) {
            float bb = bias[nt * 16 + n16];
            #pragma unroll
            for (int r = 0; r < 4; r++) {
                float v = acc[nt][r] + bb;
                out[((size_t)(bt * 8 + nt) * 16 + n16) * 1024 + (nbase + r)] = f2bf(v);
            }
        }
    } else {
        #pragma unroll
        for (int nt = 0; nt < 8; nt++) {
            float bb = bias[nt * 16 + n16];
            #pragma unroll
            for (int r = 0; r < 4; r++) {
                float v = (acc[nt][r] + bb) * scale;
                out[((size_t)(bt * 8 + nt) * 1024 + (nbase + r)) * 16 + n16] = f2bf(v);
            }
        }
    }
}

// ---------------------------------------------------------------- attention ---
// grid (16, 8, 24): x = 64-row q block, y = head, z = bt.  4 waves, 16 q-rows/wave.
// S^T = K*Q (mfma 16x16x16): C-layout lane holds q=lane&15, j=quad*4+r -> exactly
// the PV A-frag layout. exp2+pack in-register, zero P LDS traffic.
__global__ __launch_bounds__(256)
void attn_kernel(const unsigned short* __restrict__ q,
                 const unsigned short* __restrict__ k,
                 const unsigned short* __restrict__ vt,
                 float* __restrict__ O)
{
    __shared__ unsigned short Ks[256 * 20];   // K chunk [j][hd], stride 20
    __shared__ unsigned short VTs[16 * 264];  // V^T chunk [hd][j], stride 264 (16B-aligned rows)

    const int t    = threadIdx.x;
    const int wave = t >> 6, lane = t & 63, quad = lane >> 4, n16 = lane & 15;
    const int bx = blockIdx.x, h = blockIdx.y, bt = blockIdx.z;
    const size_t headoff = (size_t)(bt * 8 + h) * 16384;
    const int q0 = bx * 64 + wave * 16;

    // Q B-frag (loop-invariant): B[n=q][k=hd], lane n16 holds hd = quad*4..+3
    s16x4 qf = *(const s16x4*)(q + headoff + (size_t)(q0 + n16) * 16 + quad * 4);

    const f32x4 zero4 = {0.f, 0.f, 0.f, 0.f};
    f32x4 oacc = zero4;
    float dp = 0.f;
    const int krd = n16 * 20 + quad * 4;      // + jb*20 (imm)
    const int vrd = n16 * 264 + quad * 4;     // + jb    (imm)

    for (int c = 0; c < 4; c++) {             // 4 chunks of 256 j
        __syncthreads();
        #pragma unroll
        for (int p = 0; p < 4; p++) {         // stage K chunk: 256 rows x 4 b64 segs
            int g = p * 256 + t, row = g >> 2, qq = g & 3;
            *(s16x4*)&Ks[row * 20 + qq * 4] =
                *(const s16x4*)(k + headoff + (size_t)(c * 256 + row) * 16 + qq * 4);
        }
        #pragma unroll
        for (int p = 0; p < 2; p++) {         // stage V^T chunk: 16 rows x 32 b128 segs
            int g = p * 256 + t, row = g >> 5, seg = g & 31;
            *(s16x8*)&VTs[row * 264 + seg * 8] =
                *(const s16x8*)(vt + headoff + (size_t)row * 1024 + c * 256 + seg * 8);
        }
        __syncthreads();

        #pragma unroll
        for (int st = 0; st < 16; st++) {     // 16 subtiles of 16 j
            const int jb = st * 16;
            // K A-frag: A[m=j][k=hd]
            s16x4 kf = *(const s16x4*)&Ks[jb * 20 + krd];
            f32x4 s = mfma16(kf, qf, zero4);  // S^T tile: lane q=n16, j=jb+quad*4+r
            float p0 = __builtin_amdgcn_exp2f(s[0]);
            float p1 = __builtin_amdgcn_exp2f(s[1]);
            float p2 = __builtin_amdgcn_exp2f(s[2]);
            float p3 = __builtin_amdgcn_exp2f(s[3]);
            dp += (p0 + p1) + (p2 + p3);
            u32x2 pp = {pack_bf16(p0, p1), pack_bf16(p2, p3)};
            s16x4 pf = __builtin_bit_cast(s16x4, pp);          // PV A-frag, free
            // V B-frag: B[n=hd][k=j]
            s16x4 vf = *(const s16x4*)&VTs[jb + vrd];
            oacc = mfma16(pf, vf, oacc);      // O C-layout: lane hd=n16, q=quad*4+r
        }
    }

    // denom: reduce lane partials across quads -> dp[lane] = denom(q = lane&15)
    dp += __shfl_xor(dp, 16);
    dp += __shfl_xor(dp, 32);

    const int orow = q0 + quad * 4;
    #pragma unroll
    for (int r = 0; r < 4; r++) {
        float d = __shfl(dp, quad * 4 + r);   // denom for q-row quad*4+r
        O[((size_t)bt * 1024 + orow + r) * 128 + h * 16 + n16] = oacc[r] / d;
    }
}

// ---------------------------------------------------------------- out proj ---
__global__ __launch_bounds__(256)
void o_proj_kernel(const float* __restrict__ X, const float* __restrict__ W,
                   const float* __restrict__ bias, float* __restrict__ out)
{
    __shared__ unsigned short Xs[64 * 136];
    __shared__ unsigned short Ws[128 * 136];

    const int t  = threadIdx.x;
    const int m0 = blockIdx.x * 64;

    {
        const float4* Xg = (const float4*)(X + (size_t)m0 * 128);
        #pragma unroll
        for (int p = 0; p < 8; p++) {
            int g = p * 256 + t;
            float4 vv = Xg[g];
            int row = g >> 5, c4 = g & 31;
            ushort4 d;
            d.x = f2bf(vv.x); d.y = f2bf(vv.y); d.z = f2bf(vv.z); d.w = f2bf(vv.w);
            *(ushort4*)&Xs[row * 136 + c4 * 4] = d;
        }
        const float4* Wg = (const float4*)W;
        #pragma unroll
        for (int p = 0; p < 16; p++) {
            int g = p * 256 + t;
            float4 vv = Wg[g];
            int row = g >> 5, c4 = g & 31;
            ushort4 d;
            d.x = f2bf(vv.x); d.y = f2bf(vv.y); d.z = f2bf(vv.z); d.w = f2bf(vv.w);
            *(ushort4*)&Ws[row * 136 + c4 * 4] = d;
        }
    }
    __syncthreads();

    const int wave = t >> 6, lane = t & 63, quad = lane >> 4, n16 = lane & 15;
    f32x4 acc[8];
    const f32x4 zero4 = {0.f, 0.f, 0.f, 0.f};
    #pragma unroll
    for (int i = 0; i < 8; i++) acc[i] = zero4;

    #pragma unroll
    for (int ks = 0; ks < 4; ks++) {
        s16x8 a = *(const s16x8*)&Xs[(wave * 16 + n16) * 136 + ks * 32 + quad * 8];
        #pragma unroll
        for (int nt = 0; nt < 8; nt++) {
            s16x8 b = *(const s16x8*)&Ws[(nt * 16 + n16) * 136 + ks * 32 + quad * 8];
            acc[nt] = __builtin_amdgcn_mfma_f32_16x16x32_bf16(a, b, acc[nt], 0, 0, 0);
        }
    }

    const int mrow = m0 + wave * 16 + quad * 4;
    #pragma unroll
    for (int nt = 0; nt < 8; nt++) {
        float bb = bias[nt * 16 + n16];
        #pragma unroll
        for (int r = 0; r < 4; r++)
            out[(size_t)(mrow + r) * 128 + nt * 16 + n16] = acc[nt][r] + bb;
    }
}

// ------------------------------------------------------------------ launch ---
extern "C" void kernel_launch(void* const* d_in, const int* in_sizes, int n_in,
                              void* d_out, int out_size, void* d_ws, size_t ws_size,
                              hipStream_t stream)
{
    const float* query = (const float*)d_in[0];
    const float* key_  = (const float*)d_in[1];
    const float* value = (const float*)d_in[2];
    const float* Wq = (const float*)d_in[3];
    const float* bq = (const float*)d_in[4];
    const float* Wk = (const float*)d_in[5];
    const float* bk = (const float*)d_in[6];
    const float* Wv = (const float*)d_in[7];
    const float* bv = (const float*)d_in[8];
    const float* Wo = (const float*)d_in[9];
    const float* bo = (const float*)d_in[10];
    float* out = (float*)d_out;

    char* ws = (char*)d_ws;
    unsigned short* qb = (unsigned short*)(ws);             // [bt][h][n][hd] bf16
    unsigned short* kb = (unsigned short*)(ws + 6291456);   // [bt][h][n][hd] bf16
    unsigned short* vb = (unsigned short*)(ws + 12582912);  // [bt][h][hd][n] bf16 (transposed)
    float*          Ob = (float*)(ws + 18874368);           // [bt*1024][128] f32

    qkv_proj_kernel<<<dim3(384, 3, 1), 256, 0, stream>>>(
        query, key_, value, Wq, Wk, Wv, bq, bk, bv, qb, kb, vb);
    attn_kernel<<<dim3(16, 8, 24), 256, 0, stream>>>(qb, kb, vb, Ob);
    o_proj_kernel<<<dim3(384, 1, 1), 256, 0, stream>>>(Ob, Wo, bo, out);
}

// Round 4
// 153.884 us; speedup vs baseline: 1.1164x; 1.0541x over previous
//
#include <hip/hip_runtime.h>

// AttentionLayer: B=2,T=12,N=1024,D=128,H=8,HD=16
// qkv_proj: x@W.T+b -> bf16; q,k [bt][h][n][hd], v TRANSPOSED [bt][h][hd][n]
//   (V epilogue: lane packs 4 consecutive-n bf16 -> 1 dwordx2 store per head).
// attn: S^T = K*Q via mfma 16x16x16bf16_1k (K=HD=16). S^T C-layout == PV A-frag
//   layout, so P stays in registers (exp2 + cheap pack). O written as bf16.
// o_proj: bf16 X staging (b128 copies), f32 out.
// softmax scale 1/4*log2(e) folded into stored q (raw exp2 path).

#define DEV __device__ __forceinline__

typedef __attribute__((ext_vector_type(4))) float f32x4;
typedef __attribute__((ext_vector_type(8))) short s16x8;
typedef __attribute__((ext_vector_type(4))) short s16x4;
typedef __attribute__((ext_vector_type(2))) unsigned int u32x2;

DEV unsigned short f2bf(float f) {          // fp32 -> bf16, round-nearest-even
    unsigned u = __builtin_bit_cast(unsigned, f);
    u = (u + 0x7fffu + ((u >> 16) & 1u)) >> 16;
    return (unsigned short)u;
}

DEV unsigned pack_bf16(float a, float b) {  // {lo=bf16(a), hi=bf16(b)}
#if __has_builtin(__builtin_amdgcn_cvt_pk_bf16_f32)
    typedef __attribute__((ext_vector_type(2))) __bf16 bf16x2;
    bf16x2 t = __builtin_amdgcn_cvt_pk_bf16_f32(a, b);
    return __builtin_bit_cast(unsigned, t);
#else
    // round-half-up: +-1/2 ulp, unbiased enough; 3 VALU ops vs 7 for RNE
    unsigned ua = __builtin_bit_cast(unsigned, a) + 0x8000u;
    unsigned ub = __builtin_bit_cast(unsigned, b) + 0x8000u;
    return __builtin_amdgcn_perm(ub, ua, 0x07060302);  // {ub.hi16, ua.hi16}
#endif
}

DEV f32x4 mfma16(s16x4 a, s16x4 b, f32x4 c) {
#if __has_builtin(__builtin_amdgcn_mfma_f32_16x16x16bf16_1k)
    return __builtin_amdgcn_mfma_f32_16x16x16bf16_1k(a, b, c, 0, 0, 0);
#else
    s16x8 a8 = {a[0], a[1], a[2], a[3], 0, 0, 0, 0};
    s16x8 b8 = {b[0], b[1], b[2], b[3], 0, 0, 0, 0};
    return __builtin_amdgcn_mfma_f32_16x16x32_bf16(a8, b8, c, 0, 0, 0);
#endif
}

// ---------------------------------------------------------------- qkv proj ---
// grid (384, 3): x = 64-row tile of M=24576, y = which of q/k/v.
__global__ __launch_bounds__(256)
void qkv_proj_kernel(const float* __restrict__ xq, const float* __restrict__ xk,
                     const float* __restrict__ xv,
                     const float* __restrict__ Wq, const float* __restrict__ Wk,
                     const float* __restrict__ Wv,
                     const float* __restrict__ bq, const float* __restrict__ bk,
                     const float* __restrict__ bv,
                     unsigned short* __restrict__ oq, unsigned short* __restrict__ ok,
                     unsigned short* __restrict__ ov)
{
    const int z = blockIdx.y;
    const float* X    = (z == 0) ? xq : (z == 1) ? xk : xv;
    const float* W    = (z == 0) ? Wq : (z == 1) ? Wk : Wv;
    const float* bias = (z == 0) ? bq : (z == 1) ? bk : bv;
    unsigned short* out = (z == 0) ? oq : (z == 1) ? ok : ov;
    const float scale = (z == 0) ? 0.25f * 1.44269504088896f : 1.0f;

    __shared__ unsigned short Xs[64 * 136];
    __shared__ unsigned short Ws[128 * 136];

    const int t  = threadIdx.x;
    const int m0 = blockIdx.x * 64;

    {
        const float4* Xg = (const float4*)(X + (size_t)m0 * 128);
        #pragma unroll
        for (int p = 0; p < 8; p++) {
            int g = p * 256 + t;
            float4 vv = Xg[g];
            int row = g >> 5, c4 = g & 31;
            ushort4 d;
            d.x = f2bf(vv.x); d.y = f2bf(vv.y); d.z = f2bf(vv.z); d.w = f2bf(vv.w);
            *(ushort4*)&Xs[row * 136 + c4 * 4] = d;
        }
        const float4* Wg = (const float4*)W;
        #pragma unroll
        for (int p = 0; p < 16; p++) {
            int g = p * 256 + t;
            float4 vv = Wg[g];
            int row = g >> 5, c4 = g & 31;
            ushort4 d;
            d.x = f2bf(vv.x); d.y = f2bf(vv.y); d.z = f2bf(vv.z); d.w = f2bf(vv.w);
            *(ushort4*)&Ws[row * 136 + c4 * 4] = d;
        }
    }
    __syncthreads();

    const int wave = t >> 6, lane = t & 63, quad = lane >> 4, n16 = lane & 15;
    f32x4 acc[8];
    const f32x4 zero4 = {0.f, 0.f, 0.f, 0.f};
    #pragma unroll
    for (int i = 0; i < 8; i++) acc[i] = zero4;

    #pragma unroll
    for (int ks = 0; ks < 4; ks++) {
        s16x8 a = *(const s16x8*)&Xs[(wave * 16 + n16) * 136 + ks * 32 + quad * 8];
        #pragma unroll
        for (int nt = 0; nt < 8; nt++) {
            s16x8 b = *(const s16x8*)&Ws[(nt * 16 + n16) * 136 + ks * 32 + quad * 8];
            acc[nt] = __builtin_amdgcn_mfma_f32_16x16x32_bf16(a, b, acc[nt], 0, 0, 0);
        }
    }

    const int bt    = m0 >> 10;
    const int nbase = (m0 & 1023) + wave * 16 + quad * 4;
    if (z == 2) {
        // V transposed [bt][h][hd][n]: lane holds 4 consecutive n for hd=n16
        #pragma unroll
        for (int nt = 0; nt < 8; nt++) {
            float bb = bias[nt * 16 + n16];
            u32x2 pv = {pack_bf16(acc[nt][0] + bb, acc[nt][1] + bb),
                        pack_bf16(acc[nt][2] + bb, acc[nt][3] + bb)};
            *(u32x2*)&out[((size_t)(bt * 8 + nt) * 16 + n16) * 1024 + nbase] = pv;
        }
    } else {
        #pragma unroll
        for (int nt = 0; nt < 8; nt++) {
            float bb = bias[nt * 16 + n16];
            #pragma unroll
            for (int r = 0; r < 4; r++) {
                float v = (acc[nt][r] + bb) * scale;
                out[((size_t)(bt * 8 + nt) * 1024 + (nbase + r)) * 16 + n16] = f2bf(v);
            }
        }
    }
}

// ---------------------------------------------------------------- attention ---
// grid (16, 8, 24): x = 64-row q block, y = head, z = bt.  4 waves, 16 q-rows/wave.
__global__ __launch_bounds__(256)
void attn_kernel(const unsigned short* __restrict__ q,
                 const unsigned short* __restrict__ k,
                 const unsigned short* __restrict__ vt,
                 unsigned short* __restrict__ O)
{
    __shared__ unsigned short Ks[256 * 20];   // K chunk [j][hd], stride 20
    __shared__ unsigned short VTs[16 * 264];  // V^T chunk [hd][j], stride 264

    const int t    = threadIdx.x;
    const int wave = t >> 6, lane = t & 63, quad = lane >> 4, n16 = lane & 15;
    const int bx = blockIdx.x, h = blockIdx.y, bt = blockIdx.z;
    const size_t headoff = (size_t)(bt * 8 + h) * 16384;
    const int q0 = bx * 64 + wave * 16;

    // Q B-frag (loop-invariant): B[n=q][k=hd], lane n16 holds hd = quad*4..+3
    s16x4 qf = *(const s16x4*)(q + headoff + (size_t)(q0 + n16) * 16 + quad * 4);

    const f32x4 zero4 = {0.f, 0.f, 0.f, 0.f};
    f32x4 oacc = zero4;
    float dp = 0.f;
    const int krd = n16 * 20 + quad * 4;
    const int vrd = n16 * 264 + quad * 4;

    for (int c = 0; c < 4; c++) {             // 4 chunks of 256 j
        __syncthreads();
        #pragma unroll
        for (int p = 0; p < 4; p++) {         // stage K: 256 rows x 4 b64 segs
            int g = p * 256 + t, row = g >> 2, qq = g & 3;
            *(s16x4*)&Ks[row * 20 + qq * 4] =
                *(const s16x4*)(k + headoff + (size_t)(c * 256 + row) * 16 + qq * 4);
        }
        #pragma unroll
        for (int p = 0; p < 2; p++) {         // stage V^T: 16 rows x 32 b128 segs
            int g = p * 256 + t, row = g >> 5, seg = g & 31;
            *(s16x8*)&VTs[row * 264 + seg * 8] =
                *(const s16x8*)(vt + headoff + (size_t)row * 1024 + c * 256 + seg * 8);
        }
        __syncthreads();

        #pragma unroll
        for (int st = 0; st < 16; st++) {     // 16 subtiles of 16 j
            const int jb = st * 16;
            s16x4 kf = *(const s16x4*)&Ks[jb * 20 + krd];   // A[m=j][k=hd]
            f32x4 s = mfma16(kf, qf, zero4);  // S^T: lane q=n16, j=jb+quad*4+r
            float p0 = __builtin_amdgcn_exp2f(s[0]);
            float p1 = __builtin_amdgcn_exp2f(s[1]);
            float p2 = __builtin_amdgcn_exp2f(s[2]);
            float p3 = __builtin_amdgcn_exp2f(s[3]);
            dp += (p0 + p1) + (p2 + p3);
            u32x2 pp = {pack_bf16(p0, p1), pack_bf16(p2, p3)};
            s16x4 pf = __builtin_bit_cast(s16x4, pp);       // PV A-frag, free
            s16x4 vf = *(const s16x4*)&VTs[jb + vrd];       // B[n=hd][k=j]
            oacc = mfma16(pf, vf, oacc);      // O: lane hd=n16, q=quad*4+r
        }
    }

    // denom: reduce lane partials across quads -> dp[lane] = denom(q = lane&15)
    dp += __shfl_xor(dp, 16);
    dp += __shfl_xor(dp, 32);

    const int orow = q0 + quad * 4;
    #pragma unroll
    for (int r = 0; r < 4; r++) {
        float d = __shfl(dp, quad * 4 + r);   // denom for q-row quad*4+r
        float rv = oacc[r] * __builtin_amdgcn_rcpf(d);
        O[((size_t)bt * 1024 + orow + r) * 128 + h * 16 + n16] = f2bf(rv);
    }
}

// ---------------------------------------------------------------- out proj ---
// X is bf16 (attn output) -> straight b128 staging, no conversion.
__global__ __launch_bounds__(256)
void o_proj_kernel(const unsigned short* __restrict__ X, const float* __restrict__ W,
                   const float* __restrict__ bias, float* __restrict__ out)
{
    __shared__ unsigned short Xs[64 * 136];
    __shared__ unsigned short Ws[128 * 136];

    const int t  = threadIdx.x;
    const int m0 = blockIdx.x * 64;

    {
        #pragma unroll
        for (int p = 0; p < 4; p++) {          // 64x128 bf16: 1024 b128 chunks
            int g = p * 256 + t, row = g >> 4, ch = g & 15;
            *(s16x8*)&Xs[row * 136 + ch * 8] =
                *(const s16x8*)(X + (size_t)(m0 + row) * 128 + ch * 8);
        }
        const float4* Wg = (const float4*)W;
        #pragma unroll
        for (int p = 0; p < 16; p++) {
            int g = p * 256 + t;
            float4 vv = Wg[g];
            int row = g >> 5, c4 = g & 31;
            ushort4 d;
            d.x = f2bf(vv.x); d.y = f2bf(vv.y); d.z = f2bf(vv.z); d.w = f2bf(vv.w);
            *(ushort4*)&Ws[row * 136 + c4 * 4] = d;
        }
    }
    __syncthreads();

    const int wave = t >> 6, lane = t & 63, quad = lane >> 4, n16 = lane & 15;
    f32x4 acc[8];
    const f32x4 zero4 = {0.f, 0.f, 0.f, 0.f};
    #pragma unroll
    for (int i = 0; i < 8; i++) acc[i] = zero4;

    #pragma unroll
    for (int ks = 0; ks < 4; ks++) {
        s16x8 a = *(const s16x8*)&Xs[(wave * 16 + n16) * 136 + ks * 32 + quad * 8];
        #pragma unroll
        for (int nt = 0; nt < 8; nt++) {
            s16x8 b = *(const s16x8*)&Ws[(nt * 16 + n16) * 136 + ks * 32 + quad * 8];
            acc[nt] = __builtin_amdgcn_mfma_f32_16x16x32_bf16(a, b, acc[nt], 0, 0, 0);
        }
    }

    const int mrow = m0 + wave * 16 + quad * 4;
    #pragma unroll
    for (int nt = 0; nt < 8; nt++) {
        float bb = bias[nt * 16 + n16];
        #pragma unroll
        for (int r = 0; r < 4; r++)
            out[(size_t)(mrow + r) * 128 + nt * 16 + n16] = acc[nt][r] + bb;
    }
}

// ------------------------------------------------------------------ launch ---
extern "C" void kernel_launch(void* const* d_in, const int* in_sizes, int n_in,
                              void* d_out, int out_size, void* d_ws, size_t ws_size,
                              hipStream_t stream)
{
    const float* query = (const float*)d_in[0];
    const float* key_  = (const float*)d_in[1];
    const float* value = (const float*)d_in[2];
    const float* Wq = (const float*)d_in[3];
    const float* bq = (const float*)d_in[4];
    const float* Wk = (const float*)d_in[5];
    const float* bk = (const float*)d_in[6];
    const float* Wv = (const float*)d_in[7];
    const float* bv = (const float*)d_in[8];
    const float* Wo = (const float*)d_in[9];
    const float* bo = (const float*)d_in[10];
    float* out = (float*)d_out;

    char* ws = (char*)d_ws;
    unsigned short* qb = (unsigned short*)(ws);             // [bt][h][n][hd] bf16
    unsigned short* kb = (unsigned short*)(ws + 6291456);   // [bt][h][n][hd] bf16
    unsigned short* vb = (unsigned short*)(ws + 12582912);  // [bt][h][hd][n] bf16
    unsigned short* Ob = (unsigned short*)(ws + 18874368);  // [bt*1024][128] bf16

    qkv_proj_kernel<<<dim3(384, 3, 1), 256, 0, stream>>>(
        query, key_, value, Wq, Wk, Wv, bq, bk, bv, qb, kb, vb);
    attn_kernel<<<dim3(16, 8, 24), 256, 0, stream>>>(qb, kb, vb, Ob);
    o_proj_kernel<<<dim3(384, 1, 1), 256, 0, stream>>>(Ob, Wo, bo, out);
}

// Round 5
// 152.351 us; speedup vs baseline: 1.1276x; 1.0101x over previous
//
#include <hip/hip_runtime.h>

// AttentionLayer: B=2,T=12,N=1024,D=128,H=8,HD=16
// attn: S^T = K*Q via 2x mfma 16x16x16 with K rows PERMUTED in LDS so the two
// S^T tiles give each quad j=8q..8q+7 == 16x16x32 A-frag layout. PV and the
// softmax denominator are then single 16x16x32 MFMAs per 32 j (denominator via
// all-ones B-frag; no epilogue shuffles). P never leaves registers.
// qkv_proj: q/k epilogue transposes through LDS -> coalesced b128 stores.
// softmax scale 1/4*log2(e) folded into stored q (raw exp2 path).

#define DEV __device__ __forceinline__

typedef __attribute__((ext_vector_type(4))) float f32x4;
typedef __attribute__((ext_vector_type(8))) short s16x8;
typedef __attribute__((ext_vector_type(4))) short s16x4;
typedef __attribute__((ext_vector_type(2))) unsigned int u32x2;
typedef __attribute__((ext_vector_type(4))) unsigned int u32x4;

DEV unsigned short f2bf(float f) {          // fp32 -> bf16, round-nearest-even
    unsigned u = __builtin_bit_cast(unsigned, f);
    u = (u + 0x7fffu + ((u >> 16) & 1u)) >> 16;
    return (unsigned short)u;
}

DEV unsigned pack_bf16(float a, float b) {  // {lo=bf16(a), hi=bf16(b)}
#if __has_builtin(__builtin_amdgcn_cvt_pk_bf16_f32)
    typedef __attribute__((ext_vector_type(2))) __bf16 bf16x2;
    bf16x2 t = __builtin_amdgcn_cvt_pk_bf16_f32(a, b);
    return __builtin_bit_cast(unsigned, t);
#else
    // round-half-up: 3 VALU ops; bias cancels in softmax ratio (R4: absmax ok)
    unsigned ua = __builtin_bit_cast(unsigned, a) + 0x8000u;
    unsigned ub = __builtin_bit_cast(unsigned, b) + 0x8000u;
    return __builtin_amdgcn_perm(ub, ua, 0x07060302);  // {ub.hi16, ua.hi16}
#endif
}

DEV f32x4 mfma16(s16x4 a, s16x4 b, f32x4 c) {
#if __has_builtin(__builtin_amdgcn_mfma_f32_16x16x16bf16_1k)
    return __builtin_amdgcn_mfma_f32_16x16x16bf16_1k(a, b, c, 0, 0, 0);
#else
    s16x8 a8 = {a[0], a[1], a[2], a[3], 0, 0, 0, 0};
    s16x8 b8 = {b[0], b[1], b[2], b[3], 0, 0, 0, 0};
    return __builtin_amdgcn_mfma_f32_16x16x32_bf16(a8, b8, c, 0, 0, 0);
#endif
}

DEV f32x4 mfma32(s16x8 a, s16x8 b, f32x4 c) {
    return __builtin_amdgcn_mfma_f32_16x16x32_bf16(a, b, c, 0, 0, 0);
}

// ---------------------------------------------------------------- qkv proj ---
// grid (384, 3): x = 64-row tile of M=24576, y = which of q/k/v.
__global__ __launch_bounds__(256)
void qkv_proj_kernel(const float* __restrict__ xq, const float* __restrict__ xk,
                     const float* __restrict__ xv,
                     const float* __restrict__ Wq, const float* __restrict__ Wk,
                     const float* __restrict__ Wv,
                     const float* __restrict__ bq, const float* __restrict__ bk,
                     const float* __restrict__ bv,
                     unsigned short* __restrict__ oq, unsigned short* __restrict__ ok,
                     unsigned short* __restrict__ ov)
{
    const int z = blockIdx.y;
    const float* X    = (z == 0) ? xq : (z == 1) ? xk : xv;
    const float* W    = (z == 0) ? Wq : (z == 1) ? Wk : Wv;
    const float* bias = (z == 0) ? bq : (z == 1) ? bk : bv;
    unsigned short* out = (z == 0) ? oq : (z == 1) ? ok : ov;
    const float scale = (z == 0) ? 0.25f * 1.44269504088896f : 1.0f;

    __shared__ unsigned short Xs[64 * 136];
    __shared__ unsigned short Ws[128 * 136];

    const int t  = threadIdx.x;
    const int m0 = blockIdx.x * 64;

    {
        const float4* Xg = (const float4*)(X + (size_t)m0 * 128);
        #pragma unroll
        for (int p = 0; p < 8; p++) {
            int g = p * 256 + t;
            float4 vv = Xg[g];
            int row = g >> 5, c4 = g & 31;
            ushort4 d;
            d.x = f2bf(vv.x); d.y = f2bf(vv.y); d.z = f2bf(vv.z); d.w = f2bf(vv.w);
            *(ushort4*)&Xs[row * 136 + c4 * 4] = d;
        }
        const float4* Wg = (const float4*)W;
        #pragma unroll
        for (int p = 0; p < 16; p++) {
            int g = p * 256 + t;
            float4 vv = Wg[g];
            int row = g >> 5, c4 = g & 31;
            ushort4 d;
            d.x = f2bf(vv.x); d.y = f2bf(vv.y); d.z = f2bf(vv.z); d.w = f2bf(vv.w);
            *(ushort4*)&Ws[row * 136 + c4 * 4] = d;
        }
    }
    __syncthreads();

    const int wave = t >> 6, lane = t & 63, quad = lane >> 4, n16 = lane & 15;
    f32x4 acc[8];
    const f32x4 zero4 = {0.f, 0.f, 0.f, 0.f};
    #pragma unroll
    for (int i = 0; i < 8; i++) acc[i] = zero4;

    #pragma unroll
    for (int ks = 0; ks < 4; ks++) {
        s16x8 a = *(const s16x8*)&Xs[(wave * 16 + n16) * 136 + ks * 32 + quad * 8];
        #pragma unroll
        for (int nt = 0; nt < 8; nt++) {
            s16x8 b = *(const s16x8*)&Ws[(nt * 16 + n16) * 136 + ks * 32 + quad * 8];
            acc[nt] = __builtin_amdgcn_mfma_f32_16x16x32_bf16(a, b, acc[nt], 0, 0, 0);
        }
    }

    const int bt    = m0 >> 10;
    const int nbase = (m0 & 1023) + wave * 16 + quad * 4;
    if (z == 2) {
        // V transposed [bt][h][hd][n]: lane holds 4 consecutive n for hd=n16
        #pragma unroll
        for (int nt = 0; nt < 8; nt++) {
            float bb = bias[nt * 16 + n16];
            u32x2 pv = {pack_bf16(acc[nt][0] + bb, acc[nt][1] + bb),
                        pack_bf16(acc[nt][2] + bb, acc[nt][3] + bb)};
            *(u32x2*)&out[((size_t)(bt * 8 + nt) * 16 + n16) * 1024 + nbase] = pv;
        }
    } else {
        // q/k [bt][h][n][hd]: transpose through Xs (done with it) -> coalesced stores
        __syncthreads();
        const int crow = wave * 16 + quad * 4;
        #pragma unroll
        for (int nt = 0; nt < 8; nt++) {
            float bb = bias[nt * 16 + n16];
            #pragma unroll
            for (int r = 0; r < 4; r++)
                Xs[(crow + r) * 136 + nt * 16 + n16] = f2bf((acc[nt][r] + bb) * scale);
        }
        __syncthreads();
        #pragma unroll
        for (int p = 0; p < 4; p++) {
            int g = p * 256 + t, row = g >> 4, ch = g & 15;   // ch*8 = h*16 + seg
            s16x8 val = *(const s16x8*)&Xs[row * 136 + ch * 8];
            *(s16x8*)&out[((size_t)(bt * 8 + (ch >> 1)) * 1024 + (m0 & 1023) + row) * 16
                          + (ch & 1) * 8] = val;
        }
    }
}

// ---------------------------------------------------------------- attention ---
// grid (16, 8, 24): x = 64-row q block, y = head, z = bt.  4 waves, 16 q-rows/wave.
// K rows permuted per 32-group: j=8q+r -> slot 4q+r (tile0), j=8q+4+r -> tile1.
__global__ __launch_bounds__(256)
void attn_kernel(const unsigned short* __restrict__ q,
                 const unsigned short* __restrict__ k,
                 const unsigned short* __restrict__ vt,
                 unsigned short* __restrict__ O)
{
    __shared__ unsigned short Ks[256 * 20];   // K chunk [j'][hd], stride 20 (permuted rows)
    __shared__ unsigned short VTs[16 * 264];  // V^T chunk [hd][j], stride 264

    const int t    = threadIdx.x;
    const int wave = t >> 6, lane = t & 63, quad = lane >> 4, n16 = lane & 15;
    const int bx = blockIdx.x, h = blockIdx.y, bt = blockIdx.z;
    const size_t headoff = (size_t)(bt * 8 + h) * 16384;
    const int q0 = bx * 64 + wave * 16;

    // Q B-frag (loop-invariant): B[n=q][k=hd], lane n16 holds hd = quad*4..+3
    s16x4 qf = *(const s16x4*)(q + headoff + (size_t)(q0 + n16) * 16 + quad * 4);

    const f32x4 zero4 = {0.f, 0.f, 0.f, 0.f};
    f32x4 oacc = zero4, dacc = zero4;
    const s16x8 ones = {0x3F80, 0x3F80, 0x3F80, 0x3F80,
                        0x3F80, 0x3F80, 0x3F80, 0x3F80};   // bf16 1.0 x8
    const int krd = n16 * 20 + quad * 4;
    const int vrd = n16 * 264 + quad * 8;

    for (int c = 0; c < 4; c++) {             // 4 chunks of 256 j
        __syncthreads();
        #pragma unroll
        for (int p = 0; p < 4; p++) {         // stage K: permuted rows, b64 segs
            int g = p * 256 + t, rr = g >> 2, qq = g & 3;
            int r5 = rr & 31;
            int lrow = (rr & ~31) + ((r5 & 4) << 2) + ((r5 >> 3) << 2) + (r5 & 3);
            *(s16x4*)&Ks[lrow * 20 + qq * 4] =
                *(const s16x4*)(k + headoff + (size_t)(c * 256 + rr) * 16 + qq * 4);
        }
        #pragma unroll
        for (int p = 0; p < 2; p++) {         // stage V^T: 16 rows x 32 b128 segs
            int g = p * 256 + t, row = g >> 5, seg = g & 31;
            *(s16x8*)&VTs[row * 264 + seg * 8] =
                *(const s16x8*)(vt + headoff + (size_t)row * 1024 + c * 256 + seg * 8);
        }
        __syncthreads();

        #pragma unroll
        for (int w = 0; w < 8; w++) {         // 8 windows of 32 j
            const int jb = w * 32;
            s16x4 kf0 = *(const s16x4*)&Ks[jb * 20 + krd];         // tile0: j=8q+r
            s16x4 kf1 = *(const s16x4*)&Ks[(jb + 16) * 20 + krd];  // tile1: j=8q+4+r
            f32x4 s0 = mfma16(kf0, qf, zero4);
            f32x4 s1 = mfma16(kf1, qf, zero4);
            float p0 = __builtin_amdgcn_exp2f(s0[0]);
            float p1 = __builtin_amdgcn_exp2f(s0[1]);
            float p2 = __builtin_amdgcn_exp2f(s0[2]);
            float p3 = __builtin_amdgcn_exp2f(s0[3]);
            float p4 = __builtin_amdgcn_exp2f(s1[0]);
            float p5 = __builtin_amdgcn_exp2f(s1[1]);
            float p6 = __builtin_amdgcn_exp2f(s1[2]);
            float p7 = __builtin_amdgcn_exp2f(s1[3]);
            u32x4 pp = {pack_bf16(p0, p1), pack_bf16(p2, p3),
                        pack_bf16(p4, p5), pack_bf16(p6, p7)};
            s16x8 pf = __builtin_bit_cast(s16x8, pp);   // x32 A-frag: k=quad*8+i ✓
            s16x8 vf = *(const s16x8*)&VTs[jb + vrd];   // B[n=hd][k=j], b128
            oacc = mfma32(pf, vf, oacc);                // O: lane hd=n16, q=quad*4+r
            dacc = mfma32(pf, ones, dacc);              // denom, same row mapping
        }
    }

    // dacc[r] is already the denominator for oacc[r]'s q-row — no shuffles.
    const int orow = q0 + quad * 4;
    #pragma unroll
    for (int r = 0; r < 4; r++) {
        float rv = oacc[r] * __builtin_amdgcn_rcpf(dacc[r]);
        O[((size_t)bt * 1024 + orow + r) * 128 + h * 16 + n16] = f2bf(rv);
    }
}

// ---------------------------------------------------------------- out proj ---
// X is bf16 (attn output) -> straight b128 staging, no conversion.
__global__ __launch_bounds__(256)
void o_proj_kernel(const unsigned short* __restrict__ X, const float* __restrict__ W,
                   const float* __restrict__ bias, float* __restrict__ out)
{
    __shared__ unsigned short Xs[64 * 136];
    __shared__ unsigned short Ws[128 * 136];

    const int t  = threadIdx.x;
    const int m0 = blockIdx.x * 64;

    {
        #pragma unroll
        for (int p = 0; p < 4; p++) {          // 64x128 bf16: 1024 b128 chunks
            int g = p * 256 + t, row = g >> 4, ch = g & 15;
            *(s16x8*)&Xs[row * 136 + ch * 8] =
                *(const s16x8*)(X + (size_t)(m0 + row) * 128 + ch * 8);
        }
        const float4* Wg = (const float4*)W;
        #pragma unroll
        for (int p = 0; p < 16; p++) {
            int g = p * 256 + t;
            float4 vv = Wg[g];
            int row = g >> 5, c4 = g & 31;
            ushort4 d;
            d.x = f2bf(vv.x); d.y = f2bf(vv.y); d.z = f2bf(vv.z); d.w = f2bf(vv.w);
            *(ushort4*)&Ws[row * 136 + c4 * 4] = d;
        }
    }
    __syncthreads();

    const int wave = t >> 6, lane = t & 63, quad = lane >> 4, n16 = lane & 15;
    f32x4 acc[8];
    const f32x4 zero4 = {0.f, 0.f, 0.f, 0.f};
    #pragma unroll
    for (int i = 0; i < 8; i++) acc[i] = zero4;

    #pragma unroll
    for (int ks = 0; ks < 4; ks++) {
        s16x8 a = *(const s16x8*)&Xs[(wave * 16 + n16) * 136 + ks * 32 + quad * 8];
        #pragma unroll
        for (int nt = 0; nt < 8; nt++) {
            s16x8 b = *(const s16x8*)&Ws[(nt * 16 + n16) * 136 + ks * 32 + quad * 8];
            acc[nt] = __builtin_amdgcn_mfma_f32_16x16x32_bf16(a, b, acc[nt], 0, 0, 0);
        }
    }

    const int mrow = m0 + wave * 16 + quad * 4;
    #pragma unroll
    for (int nt = 0; nt < 8; nt++) {
        float bb = bias[nt * 16 + n16];
        #pragma unroll
        for (int r = 0; r < 4; r++)
            out[(size_t)(mrow + r) * 128 + nt * 16 + n16] = acc[nt][r] + bb;
    }
}

// ------------------------------------------------------------------ launch ---
extern "C" void kernel_launch(void* const* d_in, const int* in_sizes, int n_in,
                              void* d_out, int out_size, void* d_ws, size_t ws_size,
                              hipStream_t stream)
{
    const float* query = (const float*)d_in[0];
    const float* key_  = (const float*)d_in[1];
    const float* value = (const float*)d_in[2];
    const float* Wq = (const float*)d_in[3];
    const float* bq = (const float*)d_in[4];
    const float* Wk = (const float*)d_in[5];
    const float* bk = (const float*)d_in[6];
    const float* Wv = (const float*)d_in[7];
    const float* bv = (const float*)d_in[8];
    const float* Wo = (const float*)d_in[9];
    const float* bo = (const float*)d_in[10];
    float* out = (float*)d_out;

    char* ws = (char*)d_ws;
    unsigned short* qb = (unsigned short*)(ws);             // [bt][h][n][hd] bf16
    unsigned short* kb = (unsigned short*)(ws + 6291456);   // [bt][h][n][hd] bf16
    unsigned short* vb = (unsigned short*)(ws + 12582912);  // [bt][h][hd][n] bf16
    unsigned short* Ob = (unsigned short*)(ws + 18874368);  // [bt*1024][128] bf16

    qkv_proj_kernel<<<dim3(384, 3, 1), 256, 0, stream>>>(
        query, key_, value, Wq, Wk, Wv, bq, bk, bv, qb, kb, vb);
    attn_kernel<<<dim3(16, 8, 24), 256, 0, stream>>>(qb, kb, vb, Ob);
    o_proj_kernel<<<dim3(384, 1, 1), 256, 0, stream>>>(Ob, Wo, bo, out);
}

// Round 6
// 146.605 us; speedup vs baseline: 1.1718x; 1.0392x over previous
//
#include <hip/hip_runtime.h>

// AttentionLayer: B=2,T=12,N=1024,D=128,H=8,HD=16
// attn: S^T = K*Q via 2x mfma 16x16x16; K row-permutation folded into the
// loop-invariant LDS read base (staging is straight b64 copies). S^T C-layout
// == 16x16x32 A-frag layout, so PV + denominator are single x32 MFMAs per
// 32 j (denominator via all-ones B; no epilogue shuffles). P stays in regs.
// K/V LDS double-buffered: one __syncthreads per 256-j chunk; next chunk's
// global loads issue before compute and land in the alternate buffer after.
// qkv_proj: q/k via LDS-transpose -> coalesced b128; v transposed [bt][h][hd][n].
// softmax scale 1/4*log2(e) folded into stored q (raw exp2 path).

#define DEV __device__ __forceinline__

typedef __attribute__((ext_vector_type(4))) float f32x4;
typedef __attribute__((ext_vector_type(8))) short s16x8;
typedef __attribute__((ext_vector_type(4))) short s16x4;
typedef __attribute__((ext_vector_type(2))) unsigned int u32x2;
typedef __attribute__((ext_vector_type(4))) unsigned int u32x4;

DEV unsigned short f2bf(float f) {          // fp32 -> bf16, round-nearest-even
    unsigned u = __builtin_bit_cast(unsigned, f);
    u = (u + 0x7fffu + ((u >> 16) & 1u)) >> 16;
    return (unsigned short)u;
}

DEV unsigned pack_bf16(float a, float b) {  // {lo=bf16(a), hi=bf16(b)}
#if __has_builtin(__builtin_amdgcn_cvt_pk_bf16_f32)
    typedef __attribute__((ext_vector_type(2))) __bf16 bf16x2;
    bf16x2 t = __builtin_amdgcn_cvt_pk_bf16_f32(a, b);
    return __builtin_bit_cast(unsigned, t);
#else
    // round-half-up: 3 VALU ops; bias cancels in softmax ratio (R4/R5: absmax ok)
    unsigned ua = __builtin_bit_cast(unsigned, a) + 0x8000u;
    unsigned ub = __builtin_bit_cast(unsigned, b) + 0x8000u;
    return __builtin_amdgcn_perm(ub, ua, 0x07060302);  // {ub.hi16, ua.hi16}
#endif
}

DEV f32x4 mfma16(s16x4 a, s16x4 b, f32x4 c) {
#if __has_builtin(__builtin_amdgcn_mfma_f32_16x16x16bf16_1k)
    return __builtin_amdgcn_mfma_f32_16x16x16bf16_1k(a, b, c, 0, 0, 0);
#else
    s16x8 a8 = {a[0], a[1], a[2], a[3], 0, 0, 0, 0};
    s16x8 b8 = {b[0], b[1], b[2], b[3], 0, 0, 0, 0};
    return __builtin_amdgcn_mfma_f32_16x16x32_bf16(a8, b8, c, 0, 0, 0);
#endif
}

DEV f32x4 mfma32(s16x8 a, s16x8 b, f32x4 c) {
    return __builtin_amdgcn_mfma_f32_16x16x32_bf16(a, b, c, 0, 0, 0);
}

// ---------------------------------------------------------------- qkv proj ---
// grid (384, 3): x = 64-row tile of M=24576, y = which of q/k/v.
__global__ __launch_bounds__(256)
void qkv_proj_kernel(const float* __restrict__ xq, const float* __restrict__ xk,
                     const float* __restrict__ xv,
                     const float* __restrict__ Wq, const float* __restrict__ Wk,
                     const float* __restrict__ Wv,
                     const float* __restrict__ bq, const float* __restrict__ bk,
                     const float* __restrict__ bv,
                     unsigned short* __restrict__ oq, unsigned short* __restrict__ ok,
                     unsigned short* __restrict__ ov)
{
    const int z = blockIdx.y;
    const float* X    = (z == 0) ? xq : (z == 1) ? xk : xv;
    const float* W    = (z == 0) ? Wq : (z == 1) ? Wk : Wv;
    const float* bias = (z == 0) ? bq : (z == 1) ? bk : bv;
    unsigned short* out = (z == 0) ? oq : (z == 1) ? ok : ov;
    const float scale = (z == 0) ? 0.25f * 1.44269504088896f : 1.0f;

    __shared__ unsigned short Xs[64 * 136];
    __shared__ unsigned short Ws[128 * 136];

    const int t  = threadIdx.x;
    const int m0 = blockIdx.x * 64;

    {
        const float4* Xg = (const float4*)(X + (size_t)m0 * 128);
        #pragma unroll
        for (int p = 0; p < 8; p++) {
            int g = p * 256 + t;
            float4 vv = Xg[g];
            int row = g >> 5, c4 = g & 31;
            ushort4 d;
            d.x = f2bf(vv.x); d.y = f2bf(vv.y); d.z = f2bf(vv.z); d.w = f2bf(vv.w);
            *(ushort4*)&Xs[row * 136 + c4 * 4] = d;
        }
        const float4* Wg = (const float4*)W;
        #pragma unroll
        for (int p = 0; p < 16; p++) {
            int g = p * 256 + t;
            float4 vv = Wg[g];
            int row = g >> 5, c4 = g & 31;
            ushort4 d;
            d.x = f2bf(vv.x); d.y = f2bf(vv.y); d.z = f2bf(vv.z); d.w = f2bf(vv.w);
            *(ushort4*)&Ws[row * 136 + c4 * 4] = d;
        }
    }
    __syncthreads();

    const int wave = t >> 6, lane = t & 63, quad = lane >> 4, n16 = lane & 15;
    f32x4 acc[8];
    const f32x4 zero4 = {0.f, 0.f, 0.f, 0.f};
    #pragma unroll
    for (int i = 0; i < 8; i++) acc[i] = zero4;

    #pragma unroll
    for (int ks = 0; ks < 4; ks++) {
        s16x8 a = *(const s16x8*)&Xs[(wave * 16 + n16) * 136 + ks * 32 + quad * 8];
        #pragma unroll
        for (int nt = 0; nt < 8; nt++) {
            s16x8 b = *(const s16x8*)&Ws[(nt * 16 + n16) * 136 + ks * 32 + quad * 8];
            acc[nt] = __builtin_amdgcn_mfma_f32_16x16x32_bf16(a, b, acc[nt], 0, 0, 0);
        }
    }

    const int bt    = m0 >> 10;
    const int nbase = (m0 & 1023) + wave * 16 + quad * 4;
    if (z == 2) {
        // V transposed [bt][h][hd][n]: lane holds 4 consecutive n for hd=n16
        #pragma unroll
        for (int nt = 0; nt < 8; nt++) {
            float bb = bias[nt * 16 + n16];
            u32x2 pv = {pack_bf16(acc[nt][0] + bb, acc[nt][1] + bb),
                        pack_bf16(acc[nt][2] + bb, acc[nt][3] + bb)};
            *(u32x2*)&out[((size_t)(bt * 8 + nt) * 16 + n16) * 1024 + nbase] = pv;
        }
    } else {
        // q/k [bt][h][n][hd]: transpose through Xs (done with it) -> coalesced stores
        __syncthreads();
        const int crow = wave * 16 + quad * 4;
        #pragma unroll
        for (int nt = 0; nt < 8; nt++) {
            float bb = bias[nt * 16 + n16];
            #pragma unroll
            for (int r = 0; r < 4; r++)
                Xs[(crow + r) * 136 + nt * 16 + n16] = f2bf((acc[nt][r] + bb) * scale);
        }
        __syncthreads();
        #pragma unroll
        for (int p = 0; p < 4; p++) {
            int g = p * 256 + t, row = g >> 4, ch = g & 15;   // ch*8 = h*16 + seg
            s16x8 val = *(const s16x8*)&Xs[row * 136 + ch * 8];
            *(s16x8*)&out[((size_t)(bt * 8 + (ch >> 1)) * 1024 + (m0 & 1023) + row) * 16
                          + (ch & 1) * 8] = val;
        }
    }
}

// ---------------------------------------------------------------- attention ---
// grid (16, 8, 24): x = 64-row q block, y = head, z = bt.  4 waves, 16 q-rows/wave.
// K stored UNPERMUTED in LDS; tile permutation lives in the read base krd0.
__global__ __launch_bounds__(256)
void attn_kernel(const unsigned short* __restrict__ q,
                 const unsigned short* __restrict__ k,
                 const unsigned short* __restrict__ vt,
                 unsigned short* __restrict__ O)
{
    __shared__ unsigned short Ks[2][256 * 20];   // K chunk [j][hd], stride 20
    __shared__ unsigned short VTs[2][16 * 264];  // V^T chunk [hd][j], stride 264

    const int t    = threadIdx.x;
    const int lane = t & 63, quad = lane >> 4, n16 = lane & 15;
    const int wave = t >> 6;
    const int bx = blockIdx.x, h = blockIdx.y, bt = blockIdx.z;
    const size_t headoff = (size_t)(bt * 8 + h) * 16384;
    const int q0 = bx * 64 + wave * 16;

    // Q B-frag (loop-invariant): B[n=q][k=hd], lane n16 holds hd = quad*4..+3
    s16x4 qf = *(const s16x4*)(q + headoff + (size_t)(q0 + n16) * 16 + quad * 4);

    const f32x4 zero4 = {0.f, 0.f, 0.f, 0.f};
    f32x4 oacc = zero4, dacc = zero4;
    const s16x8 ones = {0x3F80, 0x3F80, 0x3F80, 0x3F80,
                        0x3F80, 0x3F80, 0x3F80, 0x3F80};   // bf16 1.0 x8
    // read bases: tile0 lane row j = 8*(n16>>2) + (n16&3)  (permutation folded)
    const int krd0 = (8 * (n16 >> 2) + (n16 & 3)) * 20 + quad * 4;
    const int vrd  = n16 * 264 + quad * 8;
    // staging assignments (straight copies)
    const int krow = t >> 2, kseg = (t & 3) * 4;   // K: 4 iters x (64 rows, b64)
    const int vrow = t >> 5, vseg = (t & 31) * 8;  // V: 2 iters x (8 rows, b128)
    const unsigned short* kg = k  + headoff + (size_t)krow * 16 + kseg;
    const unsigned short* vg = vt + headoff + (size_t)vrow * 1024 + vseg;

    // prologue: stage chunk 0 into buffer 0
    #pragma unroll
    for (int p = 0; p < 4; p++)
        *(s16x4*)&Ks[0][(p * 64 + krow) * 20 + kseg] =
            *(const s16x4*)(kg + (size_t)p * 1024);
    #pragma unroll
    for (int p = 0; p < 2; p++)
        *(s16x8*)&VTs[0][(p * 8 + vrow) * 264 + vseg] =
            *(const s16x8*)(vg + (size_t)p * 8192);

    #pragma unroll
    for (int c = 0; c < 4; c++) {                 // 4 chunks of 256 j
        __syncthreads();                          // buf[c&1] ready; other buf free
        s16x4 kst[4];
        s16x8 vst[2];
        if (c < 3) {                              // issue next chunk's loads now
            #pragma unroll
            for (int p = 0; p < 4; p++)
                kst[p] = *(const s16x4*)(kg + (size_t)((c + 1) * 256 + p * 64) * 16);
            #pragma unroll
            for (int p = 0; p < 2; p++)
                vst[p] = *(const s16x8*)(vg + (c + 1) * 256 + (size_t)p * 8192);
        }
        const unsigned short* Kc = Ks[c & 1];
        const unsigned short* Vc = VTs[c & 1];
        #pragma unroll
        for (int w = 0; w < 8; w++) {             // 8 windows of 32 j
            s16x4 kf0 = *(const s16x4*)&Kc[w * 640 + krd0];        // j=8a+r
            s16x4 kf1 = *(const s16x4*)&Kc[w * 640 + krd0 + 80];   // j=8a+4+r
            f32x4 s0 = mfma16(kf0, qf, zero4);
            f32x4 s1 = mfma16(kf1, qf, zero4);
            float p0 = __builtin_amdgcn_exp2f(s0[0]);
            float p1 = __builtin_amdgcn_exp2f(s0[1]);
            float p2 = __builtin_amdgcn_exp2f(s0[2]);
            float p3 = __builtin_amdgcn_exp2f(s0[3]);
            float p4 = __builtin_amdgcn_exp2f(s1[0]);
            float p5 = __builtin_amdgcn_exp2f(s1[1]);
            float p6 = __builtin_amdgcn_exp2f(s1[2]);
            float p7 = __builtin_amdgcn_exp2f(s1[3]);
            u32x4 pp = {pack_bf16(p0, p1), pack_bf16(p2, p3),
                        pack_bf16(p4, p5), pack_bf16(p6, p7)};
            s16x8 pf = __builtin_bit_cast(s16x8, pp);   // x32 A-frag: k=quad*8+i
            s16x8 vf = *(const s16x8*)&Vc[w * 32 + vrd];
            oacc = mfma32(pf, vf, oacc);          // O: lane hd=n16, q=quad*4+r
            dacc = mfma32(pf, ones, dacc);        // denom, same row mapping
        }
        if (c < 3) {                              // land prefetched chunk
            unsigned short* Kn = Ks[(c + 1) & 1];
            unsigned short* Vn = VTs[(c + 1) & 1];
            #pragma unroll
            for (int p = 0; p < 4; p++)
                *(s16x4*)&Kn[(p * 64 + krow) * 20 + kseg] = kst[p];
            #pragma unroll
            for (int p = 0; p < 2; p++)
                *(s16x8*)&Vn[(p * 8 + vrow) * 264 + vseg] = vst[p];
        }
    }

    // dacc[r] is the denominator for oacc[r]'s q-row — no shuffles.
    const int orow = q0 + quad * 4;
    #pragma unroll
    for (int r = 0; r < 4; r++) {
        float rv = oacc[r] * __builtin_amdgcn_rcpf(dacc[r]);
        O[((size_t)bt * 1024 + orow + r) * 128 + h * 16 + n16] = f2bf(rv);
    }
}

// ---------------------------------------------------------------- out proj ---
// X is bf16 (attn output) -> straight b128 staging, no conversion.
__global__ __launch_bounds__(256)
void o_proj_kernel(const unsigned short* __restrict__ X, const float* __restrict__ W,
                   const float* __restrict__ bias, float* __restrict__ out)
{
    __shared__ unsigned short Xs[64 * 136];
    __shared__ unsigned short Ws[128 * 136];

    const int t  = threadIdx.x;
    const int m0 = blockIdx.x * 64;

    {
        #pragma unroll
        for (int p = 0; p < 4; p++) {          // 64x128 bf16: 1024 b128 chunks
            int g = p * 256 + t, row = g >> 4, ch = g & 15;
            *(s16x8*)&Xs[row * 136 + ch * 8] =
                *(const s16x8*)(X + (size_t)(m0 + row) * 128 + ch * 8);
        }
        const float4* Wg = (const float4*)W;
        #pragma unroll
        for (int p = 0; p < 16; p++) {
            int g = p * 256 + t;
            float4 vv = Wg[g];
            int row = g >> 5, c4 = g & 31;
            ushort4 d;
            d.x = f2bf(vv.x); d.y = f2bf(vv.y); d.z = f2bf(vv.z); d.w = f2bf(vv.w);
            *(ushort4*)&Ws[row * 136 + c4 * 4] = d;
        }
    }
    __syncthreads();

    const int wave = t >> 6, lane = t & 63, quad = lane >> 4, n16 = lane & 15;
    f32x4 acc[8];
    const f32x4 zero4 = {0.f, 0.f, 0.f, 0.f};
    #pragma unroll
    for (int i = 0; i < 8; i++) acc[i] = zero4;

    #pragma unroll
    for (int ks = 0; ks < 4; ks++) {
        s16x8 a = *(const s16x8*)&Xs[(wave * 16 + n16) * 136 + ks * 32 + quad * 8];
        #pragma unroll
        for (int nt = 0; nt < 8; nt++) {
            s16x8 b = *(const s16x8*)&Ws[(nt * 16 + n16) * 136 + ks * 32 + quad * 8];
            acc[nt] = __builtin_amdgcn_mfma_f32_16x16x32_bf16(a, b, acc[nt], 0, 0, 0);
        }
    }

    const int mrow = m0 + wave * 16 + quad * 4;
    #pragma unroll
    for (int nt = 0; nt < 8; nt++) {
        float bb = bias[nt * 16 + n16];
        #pragma unroll
        for (int r = 0; r < 4; r++)
            out[(size_t)(mrow + r) * 128 + nt * 16 + n16] = acc[nt][r] + bb;
    }
}

// ------------------------------------------------------------------ launch ---
extern "C" void kernel_launch(void* const* d_in, const int* in_sizes, int n_in,
                              void* d_out, int out_size, void* d_ws, size_t ws_size,
                              hipStream_t stream)
{
    const float* query = (const float*)d_in[0];
    const float* key_  = (const float*)d_in[1];
    const float* value = (const float*)d_in[2];
    const float* Wq = (const float*)d_in[3];
    const float* bq = (const float*)d_in[4];
    const float* Wk = (const float*)d_in[5];
    const float* bk = (const float*)d_in[6];
    const float* Wv = (const float*)d_in[7];
    const float* bv = (const float*)d_in[8];
    const float* Wo = (const float*)d_in[9];
    const float* bo = (const float*)d_in[10];
    float* out = (float*)d_out;

    char* ws = (char*)d_ws;
    unsigned short* qb = (unsigned short*)(ws);             // [bt][h][n][hd] bf16
    unsigned short* kb = (unsigned short*)(ws + 6291456);   // [bt][h][n][hd] bf16
    unsigned short* vb = (unsigned short*)(ws + 12582912);  // [bt][h][hd][n] bf16
    unsigned short* Ob = (unsigned short*)(ws + 18874368);  // [bt*1024][128] bf16

    qkv_proj_kernel<<<dim3(384, 3, 1), 256, 0, stream>>>(
        query, key_, value, Wq, Wk, Wv, bq, bk, bv, qb, kb, vb);
    attn_kernel<<<dim3(16, 8, 24), 256, 0, stream>>>(qb, kb, vb, Ob);
    o_proj_kernel<<<dim3(384, 1, 1), 256, 0, stream>>>(Ob, Wo, bo, out);
}